// Round 15
// baseline (235.424 us; speedup 1.0000x reference)
//
#include <hip/hip_runtime.h>
#include <cstdint>
#include <cstddef>

#define T_SEQ 2048
#define BSZ 4
#define EMB 512
#define NH 8
#define HD 64
#define SCALING 0.125f
#define NEGBIG (-1e30f)
#define PW 144   // padded short-row width for Vt/Pl (288B rows)
#define PSW 67   // f32 stride of pass-2 store-staging rows (odd -> bank spread)

typedef short bf16x8_t __attribute__((ext_vector_type(8)));
typedef float f32x4_t __attribute__((ext_vector_type(4)));
typedef short short4v __attribute__((ext_vector_type(4)));
typedef float float4v __attribute__((ext_vector_type(4)));

typedef __attribute__((address_space(1))) const void* as1_cvp;
typedef __attribute__((address_space(3))) void* as3_vp;

#define MFMA16(a, b, c) __builtin_amdgcn_mfma_f32_16x16x32_bf16((a), (b), (c), 0, 0, 0)

static __device__ __forceinline__ short f2b(float f) {
  union { float f; uint32_t u; } x; x.f = f;
  uint32_t r = (x.u + 0x7fffu + ((x.u >> 16) & 1u)) >> 16;  // RNE f32->bf16
  return (short)(r & 0xffffu);
}

static __device__ __forceinline__ void gload_lds16(const void* g, void* l) {
  __builtin_amdgcn_global_load_lds((as1_cvp)g, (as3_vp)l, 16, 0, 0);
}

// ---------------------------------------------------------------------------
// Merged f32 -> bf16 conversion for all three inputs (one launch)
// ---------------------------------------------------------------------------
__global__ __launch_bounds__(256)
void cvt3_kernel(const float* __restrict__ a, const float* __restrict__ b,
                 const float* __restrict__ c, short* __restrict__ oa,
                 short* __restrict__ ob, short* __restrict__ oc) {
  const int bid = blockIdx.x;
  const float* in;
  short* out;
  int base;
  if (bid < 4096)      { in = a; out = oa; base = bid; }          // h: 8192*512
  else if (bid < 4864) { in = b; out = ob; base = bid - 4096; }   // w_in: 1536*512
  else                 { in = c; out = oc; base = bid - 4864; }   // w_out: 512*512
  int i = (base * 256 + threadIdx.x) * 4;
  float4v v = *(const float4v*)(in + i);
  short4v o;
  o[0] = f2b(v[0]); o[1] = f2b(v[1]); o[2] = f2b(v[2]); o[3] = f2b(v[3]);
  *(short4v*)(out + i) = o;
}

// ---------------------------------------------------------------------------
// NT bf16 GEMM, 128x128 tile, 4 waves, BK=32, K=512.
// CHANGED vs R14: k-loop double-buffered (T3 minimum): stage(t+1) issued
// BEFORE compute(t); ONE counted barrier per step (vmcnt covers only the
// 4 prefetch loads, which overlapped compute). Same load order -> identical.
// EPI 0: QKV scatter epilogue; EPI 1: out-proj epilogue.
// ---------------------------------------------------------------------------
template <int EPI>
__global__ __launch_bounds__(256)
void gemm_bt(const short* __restrict__ A, const short* __restrict__ Bt,
             const float* __restrict__ bias,
             short* __restrict__ outQ, short* __restrict__ outK, short* __restrict__ outV,
             float* __restrict__ outF) {
  __shared__ short ldsA[2][128 * 32];
  __shared__ short ldsB[2][128 * 32];
  const int tid = threadIdx.x;
  const int wid = tid >> 6, lane = tid & 63, g = lane >> 4, r16 = lane & 15;
  const int wr = wid >> 1, wc = wid & 1;
  const int mbase = blockIdx.y * 128, nbase = blockIdx.x * 128;

  f32x4_t acc[4][4];
#pragma unroll
  for (int m = 0; m < 4; ++m)
#pragma unroll
    for (int n = 0; n < 4; ++n) acc[m][n] = (f32x4_t){0.f, 0.f, 0.f, 0.f};

#define GSTAGE(KT, PP)                                                         \
  {                                                                            \
    _Pragma("unroll")                                                          \
    for (int i = 0; i < 2; ++i) {                                              \
      int c = i * 256 + tid;                                                   \
      int row = c >> 2, j4 = c & 3;                                            \
      gload_lds16(A + (size_t)(mbase + row) * 512 + (KT) * 32 + j4 * 8,        \
                  &ldsA[PP][c * 8]);                                           \
      gload_lds16(Bt + (size_t)(nbase + row) * 512 + (KT) * 32 + j4 * 8,       \
                  &ldsB[PP][c * 8]);                                           \
    }                                                                          \
  }

  GSTAGE(0, 0)
  asm volatile("s_waitcnt vmcnt(0)" ::: "memory");
  __builtin_amdgcn_s_barrier();
  __builtin_amdgcn_sched_barrier(0);
  int p = 0;
  for (int kt = 0; kt < 16; ++kt) {
    const bool more = (kt + 1 < 16);
    if (more) {
      GSTAGE(kt + 1, p ^ 1)                 // prefetch under compute (T3)
      __builtin_amdgcn_sched_barrier(0);    // pin: compute stays below issue
    }
    bf16x8_t af[4], bfv[4];
#pragma unroll
    for (int m = 0; m < 4; ++m)
      af[m] = *(const bf16x8_t*)&ldsA[p][(wr * 64 + m * 16 + r16) * 32 + g * 8];
#pragma unroll
    for (int n = 0; n < 4; ++n)
      bfv[n] = *(const bf16x8_t*)&ldsB[p][(wc * 64 + n * 16 + r16) * 32 + g * 8];
#pragma unroll
    for (int m = 0; m < 4; ++m)
#pragma unroll
      for (int n = 0; n < 4; ++n) acc[m][n] = MFMA16(af[m], bfv[n], acc[m][n]);
    if (more) {
      __builtin_amdgcn_sched_barrier(0);
      asm volatile("s_waitcnt vmcnt(0)" ::: "memory");  // prefetch done (overlapped)
      __builtin_amdgcn_s_barrier();
      __builtin_amdgcn_sched_barrier(0);
      p ^= 1;
    }
  }

#pragma unroll
  for (int m = 0; m < 4; ++m) {
#pragma unroll
    for (int n = 0; n < 4; ++n) {
      int col = nbase + wc * 64 + n * 16 + r16;
      float bcol = bias[col];
#pragma unroll
      for (int j = 0; j < 4; ++j) {
        int row = mbase + wr * 64 + m * 16 + g * 4 + j;
        float v = acc[m][n][j] + bcol;
        if (EPI == 0) {
          int sect = col >> 9, e = col & 511, hh = e >> 6, d = e & 63;
          int t = row >> 2, b = row & 3;
          size_t dst = ((size_t)(b * NH + hh) * T_SEQ + t) * HD + d;
          short bv = f2b(v);
          if (sect == 0) outQ[dst] = bv;
          else if (sect == 1) outK[dst] = bv;
          else outV[dst] = bv;
        } else {
          outF[(size_t)row * EMB + col] = v;
        }
      }
    }
  }
}

// ---------------------------------------------------------------------------
// Fused causal attention (R14 base: XCD head-locality swizzle, counted-vmcnt).
// CHANGED vs R14: pass-2 P stores staged in LDS (dead Pl space) and streamed
// as 4-rows x 256B-contiguous NORMAL wave stores (4x longer bursts than the
// 64B/row scattered float4s). Store count per tile stays 8 -> vmcnt(8) valid.
// ---------------------------------------------------------------------------
__global__ __launch_bounds__(256)
void attn_fused(const short* __restrict__ Qg, const short* __restrict__ Kg,
                const short* __restrict__ Vg, float* __restrict__ Pout,
                short* __restrict__ attnO) {
  __shared__ __align__(16) short lds[26624];          // 52 KB
  short* Kt = lds;                                    // 128*64 = 8192 shorts
  short* Vt = lds + 8192;                             // 64*PW  = 9216 shorts
  short(*Pl)[16 * PW] = (short(*)[16 * PW])(lds + 8192 + 9216);  // 4 waves
  // ---- XCD head-locality swizzle ----
  const int fid = (int)(blockIdx.y * gridDim.x + blockIdx.x);   // 0..1023
  const int xcd = fid & 7, slot = fid >> 3;                     // slot 0..127
  const int bh = (xcd << 2) | (slot & 3);                       // 4 heads/XCD
  const int qt = 31 - (slot >> 2);                              // big-first
  const int tid = threadIdx.x, wid = tid >> 6, lane = tid & 63;
  const int g = lane >> 4, r16 = lane & 15;
  const size_t headOff = (size_t)bh * T_SEQ * HD;
  const int wrow0 = qt * 64 + wid * 16;
  const int myrow = wrow0 + r16;
  const int maxcol = qt * 64 + 64;      // exclusive covered-column bound
  const int nt128 = (qt >> 1) + 1;      // 128-key tiles
  const short* Kh = Kg + headOff;
  const short* Vh = Vg + headOff;

  bf16x8_t qf[2];
  {
    const short* qp = Qg + headOff + (size_t)myrow * HD + g * 8;
    qf[0] = *(const bf16x8_t*)qp;
    qf[1] = *(const bf16x8_t*)(qp + 32);
  }

  float m_w = NEGBIG;   // wave-uniform running max (defer-threshold)
  float l_w = 0.f;      // per-lane partial sum of exp(S - m_w)
  f32x4_t oacc[4];
#pragma unroll
  for (int dc = 0; dc < 4; ++dc) oacc[dc] = (f32x4_t){0.f, 0.f, 0.f, 0.f};

  uint32_t* Vtu = (uint32_t*)Vt;
  const int kp0 = tid & 63, dg0 = tid >> 6;  // V staging coords

  bf16x8_t va[2], vb[2];
#define VLOAD(KB)                                                              \
  {                                                                            \
    const short* vp0 = Vh + (size_t)((KB) + kp0 * 2) * HD + dg0 * 8;           \
    va[0] = *(const bf16x8_t*)vp0; vb[0] = *(const bf16x8_t*)(vp0 + HD);       \
    const short* vp1 = vp0 + 32;                                               \
    va[1] = *(const bf16x8_t*)vp1; vb[1] = *(const bf16x8_t*)(vp1 + HD);       \
  }
  VLOAD(0)

  // ---------------- pass 1: flash (stats + O) ----------------
  for (int kt = 0; kt < nt128; ++kt) {
    const int kb = kt * 128;
    __syncthreads();                   // Vt/Kt consumed by previous tile
#pragma unroll
    for (int i = 0; i < 4; ++i) {      // K tile staging (swizzled dest rows)
      int cc = i * 256 + tid;
      int row = cc >> 3, j8 = (cc & 7) ^ (row & 7);
      gload_lds16(Kh + (size_t)(kb + row) * HD + j8 * 8, &Kt[cc * 8]);
    }
#pragma unroll
    for (int i = 0; i < 2; ++i) {      // pair-packed V transpose -> LDS
      int dg = dg0 + i * 4;
#pragma unroll
      for (int j = 0; j < 8; ++j)
        Vtu[(dg * 8 + j) * (PW / 2) + kp0] =
            (uint32_t)(uint16_t)va[i][j] | ((uint32_t)(uint16_t)vb[i][j] << 16);
    }
    __syncthreads();
    if (kt + 1 < nt128) VLOAD(kb + 128)   // prefetch next V under compute
    const int H = ((maxcol - kb) >= 128) ? 2 : 1;
#pragma unroll
    for (int h = 0; h < 2; ++h) {
      if (h < H) {
        float sv[4][4];
#pragma unroll
        for (int kc4 = 0; kc4 < 4; ++kc4) {
          const int rl = (h * 4 + kc4) * 16 + r16;
          f32x4_t s = {0.f, 0.f, 0.f, 0.f};
#pragma unroll
          for (int kk = 0; kk < 2; ++kk) {
            int byteo = (rl * 128 + kk * 64 + g * 16) ^ ((rl & 7) << 4);
            bf16x8_t kf = *(const bf16x8_t*)((const char*)Kt + byteo);
            s = MFMA16(kf, qf[kk], s);  // swapped: lane owns row myrow
          }
          const int key0 = kb + (h * 4 + kc4) * 16 + g * 4;
#pragma unroll
          for (int j = 0; j < 4; ++j)
            sv[kc4][j] = (key0 + j <= myrow) ? s[j] * SCALING : NEGBIG;
        }
        float pm = NEGBIG;
#pragma unroll
        for (int kc4 = 0; kc4 < 4; ++kc4)
#pragma unroll
          for (int j = 0; j < 4; ++j) pm = fmaxf(pm, sv[kc4][j]);
#pragma unroll
        for (int off = 1; off < 64; off <<= 1) pm = fmaxf(pm, __shfl_xor(pm, off));
        float mn = fmaxf(m_w, pm);     // wave-uniform
        if (mn > m_w + 8.f) {          // defer-max (T13): rare rescale
          float sc = __expf(m_w - mn);
          l_w *= sc;
#pragma unroll
          for (int dc = 0; dc < 4; ++dc)
#pragma unroll
            for (int j = 0; j < 4; ++j) oacc[dc][j] *= sc;
          m_w = mn;
        }
#pragma unroll
        for (int kc4 = 0; kc4 < 4; ++kc4) {
          short4v pb;
#pragma unroll
          for (int j = 0; j < 4; ++j) {
            float e = __expf(sv[kc4][j] - m_w);   // bounded by e^8
            l_w += e;
            pb[j] = f2b(e);
          }
          *(short4v*)&Pl[wid][r16 * PW + (h * 4 + kc4) * 16 + g * 4] = pb;
        }
        // per-wave Pl write->read: compiler inserts lgkmcnt (R2-R14 validated)
#pragma unroll
        for (int kk2 = 0; kk2 < 2; ++kk2) {
          const int kc2 = h * 2 + kk2;
          bf16x8_t pf = *(const bf16x8_t*)&Pl[wid][r16 * PW + kc2 * 32 + g * 8];
#pragma unroll
          for (int dc = 0; dc < 4; ++dc) {
            bf16x8_t vf = *(const bf16x8_t*)&Vt[(dc * 16 + r16) * PW + kc2 * 32 + g * 8];
            oacc[dc] = MFMA16(pf, vf, oacc[dc]);
          }
        }
      }
    }
  }

  // merge the 4 lane-groups per row (myrow shared by lanes r16, +16, +32, +48)
#pragma unroll
  for (int off = 16; off <= 32; off <<= 1) l_w += __shfl_xor(l_w, off);
  const float rl2 = 1.0f / l_w;        // frame = m_w (wave-uniform): P = e / l_w

  // O = oacc / l_w(row); rows g*4+j pull that row's l_w via shfl
  float lo[4];
#pragma unroll
  for (int j = 0; j < 4; ++j) lo[j] = 1.0f / __shfl(l_w, g * 4 + j);
#pragma unroll
  for (int dc = 0; dc < 4; ++dc) {
#pragma unroll
    for (int j = 0; j < 4; ++j) {
      int t = wrow0 + g * 4 + j, d = dc * 16 + r16;
      size_t ntok = (size_t)t * BSZ + (bh >> 3);
      attnO[ntok * EMB + (bh & 7) * HD + d] = f2b(oacc[dc][j] * lo[j]);
    }
  }

  // ------- pass 2: K-dbuf streamer, LDS-staged contiguous P stores (T4) -----
  short* Kb0 = lds;                          // overlay: Kt
  short* Kb1 = lds + 8192;                   // overlay: dead Vt space
  float* Pst = (float*)(lds + 8192 + 9216);  // overlay: dead Pl space
  float* Pstw = Pst + wid * 16 * PSW;        // this wave's [16][PSW] staging

#define STAGEK(KB, BUF)                                                        \
  {                                                                            \
    _Pragma("unroll")                                                          \
    for (int i = 0; i < 4; ++i) {                                              \
      int cc = i * 256 + tid;                                                  \
      int row = cc >> 3, j8 = (cc & 7) ^ (row & 7);                            \
      gload_lds16(Kh + (size_t)((KB) + row) * HD + j8 * 8, &(BUF)[cc * 8]);    \
    }                                                                          \
  }

  __syncthreads();           // pass-1 LDS fully consumed before restaging
  STAGEK(0, Kb0)
  __syncthreads();           // prologue full drain (incl. attnO stores) - once
  int p = 0;
  for (int kt = 0; kt < nt128; ++kt) {
    const int kb = kt * 128;
    short* cur = p ? Kb1 : Kb0;
    short* nxt = p ? Kb0 : Kb1;
    const bool more = (kt + 1 < nt128);
    if (more) {
      STAGEK(kb + 128, nxt)  // overlap staging under compute
      __builtin_amdgcn_sched_barrier(0);   // pin: stores below stay below staging
    }
    const int navail = (maxcol - kb) >> 4;
    const int H2 = (navail >= 8) ? 2 : 1;  // navail in {4,8}
#pragma unroll
    for (int h = 0; h < 2; ++h) {
      if (h < H2) {
#pragma unroll
        for (int kc4 = 0; kc4 < 4; ++kc4) {
          const int kc = h * 4 + kc4;
          const int rl = kc * 16 + r16;
          f32x4_t s = {0.f, 0.f, 0.f, 0.f};
#pragma unroll
          for (int kk = 0; kk < 2; ++kk) {
            int byteo = (rl * 128 + kk * 64 + g * 16) ^ ((rl & 7) << 4);
            bf16x8_t kf = *(const bf16x8_t*)((const char*)cur + byteo);
            s = MFMA16(kf, qf[kk], s);   // bit-identical S recompute vs pass 1
          }
          const int key0 = kb + kc * 16 + g * 4;
          float4v pvv;
#pragma unroll
          for (int j = 0; j < 4; ++j) {
            float e = __expf(s[j] * SCALING - m_w) * rl2;
            pvv[j] = (key0 + j <= myrow) ? e : 0.f;
          }
          *(float4v*)&Pstw[r16 * PSW + kc4 * 16 + g * 4] = pvv;  // stage in LDS
        }
        // stream out: 4 instrs, each 4 rows x 256B contiguous (normal stores)
#pragma unroll
        for (int i = 0; i < 4; ++i) {
          int row = i * 4 + (lane >> 4);
          int c16 = lane & 15;
          float4v t = *(const float4v*)&Pstw[row * PSW + c16 * 4];
          *(float4v*)(Pout + ((size_t)bh * T_SEQ + wrow0 + row) * T_SEQ +
                      kb + h * 64 + c16 * 4) = t;
        }
      }
    }
    if (more) {
      // exactly 8 stores issued after STAGEK (2 halves x 4) -> vmcnt(8)
      // completes the 4 staging loads while P stores stay in flight (T4)
      __builtin_amdgcn_sched_barrier(0);
      asm volatile("s_waitcnt vmcnt(8)" ::: "memory");
      __builtin_amdgcn_s_barrier();
      __builtin_amdgcn_sched_barrier(0);
    }
    p ^= 1;
  }

  // zero-fill strictly-upper P region (already contiguous; normal stores)
  const int c0 = maxcol;
  const int nc4 = (T_SEQ - c0) >> 2;
  for (int r = 0; r < 64; ++r) {
    size_t base = ((size_t)bh * T_SEQ + qt * 64 + r) * T_SEQ + c0;
    for (int c4 = tid; c4 < nc4; c4 += 256) {
      float4v z = {0.f, 0.f, 0.f, 0.f};
      *(float4v*)(Pout + base + (size_t)c4 * 4) = z;
    }
  }
}

// ---------------------------------------------------------------------------
extern "C" void kernel_launch(void* const* d_in, const int* in_sizes, int n_in,
                              void* d_out, int out_size, void* d_ws, size_t ws_size,
                              hipStream_t stream) {
  const float* h = (const float*)d_in[0];
  // d_in[1] = attn_mask (causal, applied structurally)
  const float* w_in = (const float*)d_in[2];
  const float* b_in = (const float*)d_in[3];
  const float* w_out = (const float*)d_in[4];
  const float* b_out = (const float*)d_in[5];
  float* out = (float*)d_out;
  float* Pout = out + (size_t)T_SEQ * BSZ * EMB;

  short* hB = (short*)d_ws;                      // 8192*512 bf16
  short* wB = hB + (size_t)8192 * 512;           // 1536*512
  short* owB = wB + (size_t)1536 * 512;          // 512*512
  short* qB = owB + (size_t)512 * 512;           // 32*2048*64 per-head [bh][t][d]
  short* kB = qB + (size_t)32 * 2048 * 64;
  short* vB = kB + (size_t)32 * 2048 * 64;
  short* aB = vB + (size_t)32 * 2048 * 64;       // 8192*512

  cvt3_kernel<<<5120, 256, 0, stream>>>(h, w_in, w_out, hB, wB, owB);

  gemm_bt<0><<<dim3(12, 64), 256, 0, stream>>>(hB, wB, b_in, qB, kB, vB, nullptr);
  attn_fused<<<dim3(32, 32), 256, 0, stream>>>(qB, kB, vB, Pout, aB);
  gemm_bt<1><<<dim3(4, 64), 256, 0, stream>>>(aB, owB, b_out, nullptr, nullptr, nullptr, out);
}

// Round 16
// 221.185 us; speedup vs baseline: 1.0644x; 1.0644x over previous
//
#include <hip/hip_runtime.h>
#include <cstdint>
#include <cstddef>

#define T_SEQ 2048
#define BSZ 4
#define EMB 512
#define NH 8
#define HD 64
#define SCALING 0.125f
#define NEGBIG (-1e30f)
#define PW 144   // padded short-row width for Vt/Pl (288B rows)

typedef short bf16x8_t __attribute__((ext_vector_type(8)));
typedef float f32x4_t __attribute__((ext_vector_type(4)));
typedef short short4v __attribute__((ext_vector_type(4)));
typedef float float4v __attribute__((ext_vector_type(4)));

typedef __attribute__((address_space(1))) const void* as1_cvp;
typedef __attribute__((address_space(3))) void* as3_vp;

#define MFMA16(a, b, c) __builtin_amdgcn_mfma_f32_16x16x32_bf16((a), (b), (c), 0, 0, 0)

static __device__ __forceinline__ short f2b(float f) {
  union { float f; uint32_t u; } x; x.f = f;
  uint32_t r = (x.u + 0x7fffu + ((x.u >> 16) & 1u)) >> 16;  // RNE f32->bf16
  return (short)(r & 0xffffu);
}

static __device__ __forceinline__ void gload_lds16(const void* g, void* l) {
  __builtin_amdgcn_global_load_lds((as1_cvp)g, (as3_vp)l, 16, 0, 0);
}

// ---------------------------------------------------------------------------
// Merged f32 -> bf16 conversion for all three inputs (one launch, 5120 blocks)
// ---------------------------------------------------------------------------
__global__ __launch_bounds__(256)
void cvt3_kernel(const float* __restrict__ a, const float* __restrict__ b,
                 const float* __restrict__ c, short* __restrict__ oa,
                 short* __restrict__ ob, short* __restrict__ oc) {
  const int bid = blockIdx.x;
  const float* in;
  short* out;
  int base;
  if (bid < 4096)      { in = a; out = oa; base = bid; }          // h: 8192*512
  else if (bid < 4864) { in = b; out = ob; base = bid - 4096; }   // w_in: 1536*512
  else                 { in = c; out = oc; base = bid - 4864; }   // w_out: 512*512
  int i = (base * 256 + threadIdx.x) * 4;
  float4v v = *(const float4v*)(in + i);
  short4v o;
  o[0] = f2b(v[0]); o[1] = f2b(v[1]); o[2] = f2b(v[2]); o[3] = f2b(v[3]);
  *(short4v*)(out + i) = o;
}

// ---------------------------------------------------------------------------
// NT bf16 GEMM, 128x128 tile, 4 waves, BK=32, K=512 (validated R1-R14)
// EPI 0: QKV scatter epilogue (bias add, per-head bf16 Q/K/V [bh][t][d])
// EPI 1: out-proj epilogue (bias add, f32 [row][col])
// ---------------------------------------------------------------------------
template <int EPI>
__global__ __launch_bounds__(256)
void gemm_bt(const short* __restrict__ A, const short* __restrict__ Bt,
             const float* __restrict__ bias,
             short* __restrict__ outQ, short* __restrict__ outK, short* __restrict__ outV,
             float* __restrict__ outF) {
  __shared__ short ldsA[128 * 32];
  __shared__ short ldsB[128 * 32];
  const int tid = threadIdx.x;
  const int wid = tid >> 6, lane = tid & 63, g = lane >> 4, r16 = lane & 15;
  const int wr = wid >> 1, wc = wid & 1;
  const int mbase = blockIdx.y * 128, nbase = blockIdx.x * 128;

  f32x4_t acc[4][4];
#pragma unroll
  for (int m = 0; m < 4; ++m)
#pragma unroll
    for (int n = 0; n < 4; ++n) acc[m][n] = (f32x4_t){0.f, 0.f, 0.f, 0.f};

  for (int kt = 0; kt < 16; ++kt) {
    __syncthreads();
#pragma unroll
    for (int i = 0; i < 2; ++i) {
      int c = i * 256 + tid;
      int row = c >> 2, j4 = c & 3;
      gload_lds16(A + (size_t)(mbase + row) * 512 + kt * 32 + j4 * 8, &ldsA[c * 8]);
      gload_lds16(Bt + (size_t)(nbase + row) * 512 + kt * 32 + j4 * 8, &ldsB[c * 8]);
    }
    __syncthreads();
    bf16x8_t af[4], bfv[4];
#pragma unroll
    for (int m = 0; m < 4; ++m)
      af[m] = *(const bf16x8_t*)&ldsA[(wr * 64 + m * 16 + r16) * 32 + g * 8];
#pragma unroll
    for (int n = 0; n < 4; ++n)
      bfv[n] = *(const bf16x8_t*)&ldsB[(wc * 64 + n * 16 + r16) * 32 + g * 8];
#pragma unroll
    for (int m = 0; m < 4; ++m)
#pragma unroll
      for (int n = 0; n < 4; ++n) acc[m][n] = MFMA16(af[m], bfv[n], acc[m][n]);
  }

#pragma unroll
  for (int m = 0; m < 4; ++m) {
#pragma unroll
    for (int n = 0; n < 4; ++n) {
      int col = nbase + wc * 64 + n * 16 + r16;
      float bcol = bias[col];
#pragma unroll
      for (int j = 0; j < 4; ++j) {
        int row = mbase + wr * 64 + m * 16 + g * 4 + j;
        float v = acc[m][n][j] + bcol;
        if (EPI == 0) {
          int sect = col >> 9, e = col & 511, hh = e >> 6, d = e & 63;
          int t = row >> 2, b = row & 3;
          size_t dst = ((size_t)(b * NH + hh) * T_SEQ + t) * HD + d;
          short bv = f2b(v);
          if (sect == 0) outQ[dst] = bv;
          else if (sect == 1) outK[dst] = bv;
          else outV[dst] = bv;
        } else {
          outF[(size_t)row * EMB + col] = v;
        }
      }
    }
  }
}

// ---------------------------------------------------------------------------
// Fused causal attention (R10 structure + XCD head-locality swizzle, no NT).
// Block mapping: fid = by*32+bx; xcd = fid&7 (HW round-robin); each XCD owns
//   4 heads (bh = xcd*4 + slot&3) -> per-XCD K+V+Q working set ~2.5MB < 4MB L2.
//   qt = 31-(slot>>2): big tiles first.
// Pass 1 (flash): K LDS-staged (swizzled gload_lds), V reg-prefetch -> LDS
//   pair-packed. Swapped mfma(K,Q). Wave-uniform defer-max. Pl -> PV MFMA.
// Pass 2 (streamer): K dbuf, counted-vmcnt sync (T4): vmcnt(8) keeps the 8 P
//   stores in flight across the per-tile barrier.
// ---------------------------------------------------------------------------
__global__ __launch_bounds__(256)
void attn_fused(const short* __restrict__ Qg, const short* __restrict__ Kg,
                const short* __restrict__ Vg, float* __restrict__ Pout,
                short* __restrict__ attnO) {
  __shared__ __align__(16) short lds[26624];          // 52 KB
  short* Kt = lds;                                    // 128*64 = 8192 shorts
  short* Vt = lds + 8192;                             // 64*PW  = 9216 shorts
  short(*Pl)[16 * PW] = (short(*)[16 * PW])(lds + 8192 + 9216);  // 4 waves
  // ---- XCD head-locality swizzle (T1 specialization) ----
  const int fid = (int)(blockIdx.y * gridDim.x + blockIdx.x);   // 0..1023
  const int xcd = fid & 7, slot = fid >> 3;                     // slot 0..127
  const int bh = (xcd << 2) | (slot & 3);                       // 4 heads/XCD
  const int qt = 31 - (slot >> 2);                              // big-first
  const int tid = threadIdx.x, wid = tid >> 6, lane = tid & 63;
  const int g = lane >> 4, r16 = lane & 15;
  const size_t headOff = (size_t)bh * T_SEQ * HD;
  const int wrow0 = qt * 64 + wid * 16;
  const int myrow = wrow0 + r16;
  const int maxcol = qt * 64 + 64;      // exclusive covered-column bound
  const int nt128 = (qt >> 1) + 1;      // 128-key tiles
  const short* Kh = Kg + headOff;
  const short* Vh = Vg + headOff;

  bf16x8_t qf[2];
  {
    const short* qp = Qg + headOff + (size_t)myrow * HD + g * 8;
    qf[0] = *(const bf16x8_t*)qp;
    qf[1] = *(const bf16x8_t*)(qp + 32);
  }

  float m_w = NEGBIG;   // wave-uniform running max (defer-threshold)
  float l_w = 0.f;      // per-lane partial sum of exp(S - m_w)
  f32x4_t oacc[4];
#pragma unroll
  for (int dc = 0; dc < 4; ++dc) oacc[dc] = (f32x4_t){0.f, 0.f, 0.f, 0.f};

  uint32_t* Vtu = (uint32_t*)Vt;
  const int kp0 = tid & 63, dg0 = tid >> 6;  // V staging coords

  bf16x8_t va[2], vb[2];
#define VLOAD(KB)                                                              \
  {                                                                            \
    const short* vp0 = Vh + (size_t)((KB) + kp0 * 2) * HD + dg0 * 8;           \
    va[0] = *(const bf16x8_t*)vp0; vb[0] = *(const bf16x8_t*)(vp0 + HD);       \
    const short* vp1 = vp0 + 32;                                               \
    va[1] = *(const bf16x8_t*)vp1; vb[1] = *(const bf16x8_t*)(vp1 + HD);       \
  }
  VLOAD(0)

  // ---------------- pass 1: flash (stats + O) ----------------
  for (int kt = 0; kt < nt128; ++kt) {
    const int kb = kt * 128;
    __syncthreads();                   // Vt/Kt consumed by previous tile
#pragma unroll
    for (int i = 0; i < 4; ++i) {      // K tile staging (swizzled dest rows)
      int cc = i * 256 + tid;
      int row = cc >> 3, j8 = (cc & 7) ^ (row & 7);
      gload_lds16(Kh + (size_t)(kb + row) * HD + j8 * 8, &Kt[cc * 8]);
    }
#pragma unroll
    for (int i = 0; i < 2; ++i) {      // pair-packed V transpose -> LDS
      int dg = dg0 + i * 4;
#pragma unroll
      for (int j = 0; j < 8; ++j)
        Vtu[(dg * 8 + j) * (PW / 2) + kp0] =
            (uint32_t)(uint16_t)va[i][j] | ((uint32_t)(uint16_t)vb[i][j] << 16);
    }
    __syncthreads();
    if (kt + 1 < nt128) VLOAD(kb + 128)   // prefetch next V under compute
    const int H = ((maxcol - kb) >= 128) ? 2 : 1;
#pragma unroll
    for (int h = 0; h < 2; ++h) {
      if (h < H) {
        float sv[4][4];
#pragma unroll
        for (int kc4 = 0; kc4 < 4; ++kc4) {
          const int rl = (h * 4 + kc4) * 16 + r16;
          f32x4_t s = {0.f, 0.f, 0.f, 0.f};
#pragma unroll
          for (int kk = 0; kk < 2; ++kk) {
            int byteo = (rl * 128 + kk * 64 + g * 16) ^ ((rl & 7) << 4);
            bf16x8_t kf = *(const bf16x8_t*)((const char*)Kt + byteo);
            s = MFMA16(kf, qf[kk], s);  // swapped: lane owns row myrow
          }
          const int key0 = kb + (h * 4 + kc4) * 16 + g * 4;
#pragma unroll
          for (int j = 0; j < 4; ++j)
            sv[kc4][j] = (key0 + j <= myrow) ? s[j] * SCALING : NEGBIG;
        }
        float pm = NEGBIG;
#pragma unroll
        for (int kc4 = 0; kc4 < 4; ++kc4)
#pragma unroll
          for (int j = 0; j < 4; ++j) pm = fmaxf(pm, sv[kc4][j]);
#pragma unroll
        for (int off = 1; off < 64; off <<= 1) pm = fmaxf(pm, __shfl_xor(pm, off));
        float mn = fmaxf(m_w, pm);     // wave-uniform
        if (mn > m_w + 8.f) {          // defer-max (T13): rare rescale
          float sc = __expf(m_w - mn);
          l_w *= sc;
#pragma unroll
          for (int dc = 0; dc < 4; ++dc)
#pragma unroll
            for (int j = 0; j < 4; ++j) oacc[dc][j] *= sc;
          m_w = mn;
        }
#pragma unroll
        for (int kc4 = 0; kc4 < 4; ++kc4) {
          short4v pb;
#pragma unroll
          for (int j = 0; j < 4; ++j) {
            float e = __expf(sv[kc4][j] - m_w);   // bounded by e^8
            l_w += e;
            pb[j] = f2b(e);
          }
          *(short4v*)&Pl[wid][r16 * PW + (h * 4 + kc4) * 16 + g * 4] = pb;
        }
        // per-wave Pl write->read: compiler inserts lgkmcnt (R2-R14 validated)
#pragma unroll
        for (int kk2 = 0; kk2 < 2; ++kk2) {
          const int kc2 = h * 2 + kk2;
          bf16x8_t pf = *(const bf16x8_t*)&Pl[wid][r16 * PW + kc2 * 32 + g * 8];
#pragma unroll
          for (int dc = 0; dc < 4; ++dc) {
            bf16x8_t vf = *(const bf16x8_t*)&Vt[(dc * 16 + r16) * PW + kc2 * 32 + g * 8];
            oacc[dc] = MFMA16(pf, vf, oacc[dc]);
          }
        }
      }
    }
  }

  // merge the 4 lane-groups per row (myrow shared by lanes r16, +16, +32, +48)
#pragma unroll
  for (int off = 16; off <= 32; off <<= 1) l_w += __shfl_xor(l_w, off);
  const float rl2 = 1.0f / l_w;        // frame = m_w (wave-uniform): P = e / l_w

  // O = oacc / l_w(row); rows g*4+j pull that row's l_w via shfl
  float lo[4];
#pragma unroll
  for (int j = 0; j < 4; ++j) lo[j] = 1.0f / __shfl(l_w, g * 4 + j);
#pragma unroll
  for (int dc = 0; dc < 4; ++dc) {
#pragma unroll
    for (int j = 0; j < 4; ++j) {
      int t = wrow0 + g * 4 + j, d = dc * 16 + r16;
      size_t ntok = (size_t)t * BSZ + (bh >> 3);
      attnO[ntok * EMB + (bh & 7) * HD + d] = f2b(oacc[dc][j] * lo[j]);
    }
  }

  // ---------------- pass 2: K-dbuf P streamer (counted-vmcnt sync, T4) ------
  short* Kb0 = lds;          // overlay: Kt
  short* Kb1 = lds + 8192;   // overlay: dead Vt space
  float* Prow = Pout + ((size_t)bh * T_SEQ + myrow) * T_SEQ;

#define STAGEK(KB, BUF)                                                        \
  {                                                                            \
    _Pragma("unroll")                                                          \
    for (int i = 0; i < 4; ++i) {                                              \
      int cc = i * 256 + tid;                                                  \
      int row = cc >> 3, j8 = (cc & 7) ^ (row & 7);                            \
      gload_lds16(Kh + (size_t)((KB) + row) * HD + j8 * 8, &(BUF)[cc * 8]);    \
    }                                                                          \
  }

  __syncthreads();           // pass-1 LDS fully consumed before restaging
  STAGEK(0, Kb0)
  __syncthreads();           // prologue full drain (incl. attnO stores) - once
  int p = 0;
  for (int kt = 0; kt < nt128; ++kt) {
    const int kb = kt * 128;
    short* cur = p ? Kb1 : Kb0;
    short* nxt = p ? Kb0 : Kb1;
    const bool more = (kt + 1 < nt128);
    if (more) {
      STAGEK(kb + 128, nxt)  // overlap staging under compute
      __builtin_amdgcn_sched_barrier(0);   // pin: stores below stay below staging
    }
    const int navail = (maxcol - kb) >> 4;
    const int nkc = navail < 8 ? navail : 8;
#pragma unroll
    for (int kc = 0; kc < 8; ++kc) {
      if (kc < nkc) {
        const int rl = kc * 16 + r16;
        f32x4_t s = {0.f, 0.f, 0.f, 0.f};
#pragma unroll
        for (int kk = 0; kk < 2; ++kk) {
          int byteo = (rl * 128 + kk * 64 + g * 16) ^ ((rl & 7) << 4);
          bf16x8_t kf = *(const bf16x8_t*)((const char*)cur + byteo);
          s = MFMA16(kf, qf[kk], s);   // bit-identical S recompute vs pass 1
        }
        const int key0 = kb + kc * 16 + g * 4;
        float4v pvv;
#pragma unroll
        for (int j = 0; j < 4; ++j) {
          float e = __expf(s[j] * SCALING - m_w) * rl2;
          pvv[j] = (key0 + j <= myrow) ? e : 0.f;
        }
        *(float4v*)(Prow + key0) = pvv;
      }
    }
    if (more) {
      // exactly 8 stores issued after STAGEK -> vmcnt(8) completes the 4
      // staging loads while P stores stay in flight across the barrier (T4)
      __builtin_amdgcn_sched_barrier(0);
      asm volatile("s_waitcnt vmcnt(8)" ::: "memory");
      __builtin_amdgcn_s_barrier();
      __builtin_amdgcn_sched_barrier(0);
    }
    p ^= 1;
  }

  // zero-fill strictly-upper P region
  const int c0 = maxcol;
  const int nc4 = (T_SEQ - c0) >> 2;
  for (int r = 0; r < 64; ++r) {
    size_t base = ((size_t)bh * T_SEQ + qt * 64 + r) * T_SEQ + c0;
    for (int c4 = tid; c4 < nc4; c4 += 256) {
      float4v z = {0.f, 0.f, 0.f, 0.f};
      *(float4v*)(Pout + base + (size_t)c4 * 4) = z;
    }
  }
}

// ---------------------------------------------------------------------------
extern "C" void kernel_launch(void* const* d_in, const int* in_sizes, int n_in,
                              void* d_out, int out_size, void* d_ws, size_t ws_size,
                              hipStream_t stream) {
  const float* h = (const float*)d_in[0];
  // d_in[1] = attn_mask (causal, applied structurally)
  const float* w_in = (const float*)d_in[2];
  const float* b_in = (const float*)d_in[3];
  const float* w_out = (const float*)d_in[4];
  const float* b_out = (const float*)d_in[5];
  float* out = (float*)d_out;
  float* Pout = out + (size_t)T_SEQ * BSZ * EMB;

  short* hB = (short*)d_ws;                      // 8192*512 bf16
  short* wB = hB + (size_t)8192 * 512;           // 1536*512
  short* owB = wB + (size_t)1536 * 512;          // 512*512
  short* qB = owB + (size_t)512 * 512;           // 32*2048*64 per-head [bh][t][d]
  short* kB = qB + (size_t)32 * 2048 * 64;
  short* vB = kB + (size_t)32 * 2048 * 64;
  short* aB = vB + (size_t)32 * 2048 * 64;       // 8192*512

  cvt3_kernel<<<5120, 256, 0, stream>>>(h, w_in, w_out, hB, wB, owB);

  gemm_bt<0><<<dim3(12, 64), 256, 0, stream>>>(hB, wB, b_in, qB, kB, vB, nullptr);
  attn_fused<<<dim3(32, 32), 256, 0, stream>>>(qB, kB, vB, Pout, aB);
  gemm_bt<1><<<dim3(4, 64), 256, 0, stream>>>(aB, owB, b_out, nullptr, nullptr, nullptr, out);
}

// Round 17
// 195.349 us; speedup vs baseline: 1.2051x; 1.1323x over previous
//
#include <hip/hip_runtime.h>
#include <cstdint>
#include <cstddef>

#define T_SEQ 2048
#define BSZ 4
#define EMB 512
#define NH 8
#define HD 64
#define SCALING 0.125f
#define NEGBIG (-1e30f)
#define PW 144   // padded short-row width for Vt/Pl (288B rows)

typedef short bf16x8_t __attribute__((ext_vector_type(8)));
typedef float f32x4_t __attribute__((ext_vector_type(4)));
typedef short short4v __attribute__((ext_vector_type(4)));
typedef float float4v __attribute__((ext_vector_type(4)));

typedef __attribute__((address_space(1))) const void* as1_cvp;
typedef __attribute__((address_space(3))) void* as3_vp;

#define MFMA16(a, b, c) __builtin_amdgcn_mfma_f32_16x16x32_bf16((a), (b), (c), 0, 0, 0)

static __device__ __forceinline__ short f2b(float f) {
  union { float f; uint32_t u; } x; x.f = f;
  uint32_t r = (x.u + 0x7fffu + ((x.u >> 16) & 1u)) >> 16;  // RNE f32->bf16
  return (short)(r & 0xffffu);
}

static __device__ __forceinline__ void gload_lds16(const void* g, void* l) {
  __builtin_amdgcn_global_load_lds((as1_cvp)g, (as3_vp)l, 16, 0, 0);
}

// ---------------------------------------------------------------------------
// Merged f32 -> bf16 conversion for all three inputs (one launch, 5120 blocks)
// ---------------------------------------------------------------------------
__global__ __launch_bounds__(256)
void cvt3_kernel(const float* __restrict__ a, const float* __restrict__ b,
                 const float* __restrict__ c, short* __restrict__ oa,
                 short* __restrict__ ob, short* __restrict__ oc) {
  const int bid = blockIdx.x;
  const float* in;
  short* out;
  int base;
  if (bid < 4096)      { in = a; out = oa; base = bid; }          // h: 8192*512
  else if (bid < 4864) { in = b; out = ob; base = bid - 4096; }   // w_in: 1536*512
  else                 { in = c; out = oc; base = bid - 4864; }   // w_out: 512*512
  int i = (base * 256 + threadIdx.x) * 4;
  float4v v = *(const float4v*)(in + i);
  short4v o;
  o[0] = f2b(v[0]); o[1] = f2b(v[1]); o[2] = f2b(v[2]); o[3] = f2b(v[3]);
  *(short4v*)(out + i) = o;
}

// ---------------------------------------------------------------------------
// NT bf16 GEMM, 128x128 tile, 4 waves, BK=32, K=512 (validated R1-R16)
// EPI 0: QKV scatter epilogue (bias add, per-head bf16 Q/K/V [bh][t][d])
// EPI 1: out-proj epilogue (bias add, f32 [row][col])
// ---------------------------------------------------------------------------
template <int EPI>
__global__ __launch_bounds__(256)
void gemm_bt(const short* __restrict__ A, const short* __restrict__ Bt,
             const float* __restrict__ bias,
             short* __restrict__ outQ, short* __restrict__ outK, short* __restrict__ outV,
             float* __restrict__ outF) {
  __shared__ short ldsA[128 * 32];
  __shared__ short ldsB[128 * 32];
  const int tid = threadIdx.x;
  const int wid = tid >> 6, lane = tid & 63, g = lane >> 4, r16 = lane & 15;
  const int wr = wid >> 1, wc = wid & 1;
  const int mbase = blockIdx.y * 128, nbase = blockIdx.x * 128;

  f32x4_t acc[4][4];
#pragma unroll
  for (int m = 0; m < 4; ++m)
#pragma unroll
    for (int n = 0; n < 4; ++n) acc[m][n] = (f32x4_t){0.f, 0.f, 0.f, 0.f};

  for (int kt = 0; kt < 16; ++kt) {
    __syncthreads();
#pragma unroll
    for (int i = 0; i < 2; ++i) {
      int c = i * 256 + tid;
      int row = c >> 2, j4 = c & 3;
      gload_lds16(A + (size_t)(mbase + row) * 512 + kt * 32 + j4 * 8, &ldsA[c * 8]);
      gload_lds16(Bt + (size_t)(nbase + row) * 512 + kt * 32 + j4 * 8, &ldsB[c * 8]);
    }
    __syncthreads();
    bf16x8_t af[4], bfv[4];
#pragma unroll
    for (int m = 0; m < 4; ++m)
      af[m] = *(const bf16x8_t*)&ldsA[(wr * 64 + m * 16 + r16) * 32 + g * 8];
#pragma unroll
    for (int n = 0; n < 4; ++n)
      bfv[n] = *(const bf16x8_t*)&ldsB[(wc * 64 + n * 16 + r16) * 32 + g * 8];
#pragma unroll
    for (int m = 0; m < 4; ++m)
#pragma unroll
      for (int n = 0; n < 4; ++n) acc[m][n] = MFMA16(af[m], bfv[n], acc[m][n]);
  }

#pragma unroll
  for (int m = 0; m < 4; ++m) {
#pragma unroll
    for (int n = 0; n < 4; ++n) {
      int col = nbase + wc * 64 + n * 16 + r16;
      float bcol = bias[col];
#pragma unroll
      for (int j = 0; j < 4; ++j) {
        int row = mbase + wr * 64 + m * 16 + g * 4 + j;
        float v = acc[m][n][j] + bcol;
        if (EPI == 0) {
          int sect = col >> 9, e = col & 511, hh = e >> 6, d = e & 63;
          int t = row >> 2, b = row & 3;
          size_t dst = ((size_t)(b * NH + hh) * T_SEQ + t) * HD + d;
          short bv = f2b(v);
          if (sect == 0) outQ[dst] = bv;
          else if (sect == 1) outK[dst] = bv;
          else outV[dst] = bv;
        } else {
          outF[(size_t)row * EMB + col] = v;
        }
      }
    }
  }
}

// ---------------------------------------------------------------------------
// Fused causal attention (R16 + complementary-phase scheduling).
// Block mapping: fid = by*32+bx; xcd = fid&7; bh = xcd*4 + (slot&3) (4 heads
//   per XCD, L2 locality). qt ALTERNATES big/small (s4 even -> 31-s4/2, odd ->
//   s4/2) so each CU's resident blocks mix store-heavy (small-qt: big fill)
//   with compute-heavy (big-qt: long pass-1) work -> write engine stays busy
//   during pass-1 phases. Zero-fill runs FIRST (depends only on bh,qt) so
//   fill stores stream under co-resident blocks' compute.
// Pass 1 (flash): K LDS-staged (swizzled gload_lds), V reg-prefetch -> LDS
//   pair-packed. Swapped mfma(K,Q). Wave-uniform defer-max. Pl -> PV MFMA.
// Pass 2 (streamer): K dbuf, counted-vmcnt sync (T4): vmcnt(8) keeps the 8 P
//   stores in flight across the per-tile barrier.
// ---------------------------------------------------------------------------
__global__ __launch_bounds__(256)
void attn_fused(const short* __restrict__ Qg, const short* __restrict__ Kg,
                const short* __restrict__ Vg, float* __restrict__ Pout,
                short* __restrict__ attnO) {
  __shared__ __align__(16) short lds[26624];          // 52 KB
  short* Kt = lds;                                    // 128*64 = 8192 shorts
  short* Vt = lds + 8192;                             // 64*PW  = 9216 shorts
  short(*Pl)[16 * PW] = (short(*)[16 * PW])(lds + 8192 + 9216);  // 4 waves
  // ---- XCD head-locality + alternating-phase qt order ----
  const int fid = (int)(blockIdx.y * gridDim.x + blockIdx.x);   // 0..1023
  const int xcd = fid & 7, slot = fid >> 3;                     // slot 0..127
  const int bh = (xcd << 2) | (slot & 3);                       // 4 heads/XCD
  const int s4 = slot >> 2;                                     // 0..31
  const int qt = (s4 & 1) ? (s4 >> 1) : (31 - (s4 >> 1));       // big/small mix
  const int tid = threadIdx.x, wid = tid >> 6, lane = tid & 63;
  const int g = lane >> 4, r16 = lane & 15;
  const size_t headOff = (size_t)bh * T_SEQ * HD;
  const int wrow0 = qt * 64 + wid * 16;
  const int myrow = wrow0 + r16;
  const int maxcol = qt * 64 + 64;      // exclusive covered-column bound
  const int nt128 = (qt >> 1) + 1;      // 128-key tiles
  const short* Kh = Kg + headOff;
  const short* Vh = Vg + headOff;

  // ---- zero-fill strictly-upper P region FIRST: stores stream under other
  //      blocks' pass-1 compute (no dependency on any computed value) ----
  {
    const int c0 = maxcol;
    const int nc4 = (T_SEQ - c0) >> 2;
    for (int r = 0; r < 64; ++r) {
      size_t base = ((size_t)bh * T_SEQ + qt * 64 + r) * T_SEQ + c0;
      for (int c4 = tid; c4 < nc4; c4 += 256) {
        float4v z = {0.f, 0.f, 0.f, 0.f};
        *(float4v*)(Pout + base + (size_t)c4 * 4) = z;
      }
    }
  }

  bf16x8_t qf[2];
  {
    const short* qp = Qg + headOff + (size_t)myrow * HD + g * 8;
    qf[0] = *(const bf16x8_t*)qp;
    qf[1] = *(const bf16x8_t*)(qp + 32);
  }

  float m_w = NEGBIG;   // wave-uniform running max (defer-threshold)
  float l_w = 0.f;      // per-lane partial sum of exp(S - m_w)
  f32x4_t oacc[4];
#pragma unroll
  for (int dc = 0; dc < 4; ++dc) oacc[dc] = (f32x4_t){0.f, 0.f, 0.f, 0.f};

  uint32_t* Vtu = (uint32_t*)Vt;
  const int kp0 = tid & 63, dg0 = tid >> 6;  // V staging coords

  bf16x8_t va[2], vb[2];
#define VLOAD(KB)                                                              \
  {                                                                            \
    const short* vp0 = Vh + (size_t)((KB) + kp0 * 2) * HD + dg0 * 8;           \
    va[0] = *(const bf16x8_t*)vp0; vb[0] = *(const bf16x8_t*)(vp0 + HD);       \
    const short* vp1 = vp0 + 32;                                               \
    va[1] = *(const bf16x8_t*)vp1; vb[1] = *(const bf16x8_t*)(vp1 + HD);       \
  }
  VLOAD(0)

  // ---------------- pass 1: flash (stats + O) ----------------
  for (int kt = 0; kt < nt128; ++kt) {
    const int kb = kt * 128;
    __syncthreads();                   // Vt/Kt consumed by previous tile
#pragma unroll
    for (int i = 0; i < 4; ++i) {      // K tile staging (swizzled dest rows)
      int cc = i * 256 + tid;
      int row = cc >> 3, j8 = (cc & 7) ^ (row & 7);
      gload_lds16(Kh + (size_t)(kb + row) * HD + j8 * 8, &Kt[cc * 8]);
    }
#pragma unroll
    for (int i = 0; i < 2; ++i) {      // pair-packed V transpose -> LDS
      int dg = dg0 + i * 4;
#pragma unroll
      for (int j = 0; j < 8; ++j)
        Vtu[(dg * 8 + j) * (PW / 2) + kp0] =
            (uint32_t)(uint16_t)va[i][j] | ((uint32_t)(uint16_t)vb[i][j] << 16);
    }
    __syncthreads();
    if (kt + 1 < nt128) VLOAD(kb + 128)   // prefetch next V under compute
    const int H = ((maxcol - kb) >= 128) ? 2 : 1;
#pragma unroll
    for (int h = 0; h < 2; ++h) {
      if (h < H) {
        float sv[4][4];
#pragma unroll
        for (int kc4 = 0; kc4 < 4; ++kc4) {
          const int rl = (h * 4 + kc4) * 16 + r16;
          f32x4_t s = {0.f, 0.f, 0.f, 0.f};
#pragma unroll
          for (int kk = 0; kk < 2; ++kk) {
            int byteo = (rl * 128 + kk * 64 + g * 16) ^ ((rl & 7) << 4);
            bf16x8_t kf = *(const bf16x8_t*)((const char*)Kt + byteo);
            s = MFMA16(kf, qf[kk], s);  // swapped: lane owns row myrow
          }
          const int key0 = kb + (h * 4 + kc4) * 16 + g * 4;
#pragma unroll
          for (int j = 0; j < 4; ++j)
            sv[kc4][j] = (key0 + j <= myrow) ? s[j] * SCALING : NEGBIG;
        }
        float pm = NEGBIG;
#pragma unroll
        for (int kc4 = 0; kc4 < 4; ++kc4)
#pragma unroll
          for (int j = 0; j < 4; ++j) pm = fmaxf(pm, sv[kc4][j]);
#pragma unroll
        for (int off = 1; off < 64; off <<= 1) pm = fmaxf(pm, __shfl_xor(pm, off));
        float mn = fmaxf(m_w, pm);     // wave-uniform
        if (mn > m_w + 8.f) {          // defer-max (T13): rare rescale
          float sc = __expf(m_w - mn);
          l_w *= sc;
#pragma unroll
          for (int dc = 0; dc < 4; ++dc)
#pragma unroll
            for (int j = 0; j < 4; ++j) oacc[dc][j] *= sc;
          m_w = mn;
        }
#pragma unroll
        for (int kc4 = 0; kc4 < 4; ++kc4) {
          short4v pb;
#pragma unroll
          for (int j = 0; j < 4; ++j) {
            float e = __expf(sv[kc4][j] - m_w);   // bounded by e^8
            l_w += e;
            pb[j] = f2b(e);
          }
          *(short4v*)&Pl[wid][r16 * PW + (h * 4 + kc4) * 16 + g * 4] = pb;
        }
        // per-wave Pl write->read: compiler inserts lgkmcnt (R2-R16 validated)
#pragma unroll
        for (int kk2 = 0; kk2 < 2; ++kk2) {
          const int kc2 = h * 2 + kk2;
          bf16x8_t pf = *(const bf16x8_t*)&Pl[wid][r16 * PW + kc2 * 32 + g * 8];
#pragma unroll
          for (int dc = 0; dc < 4; ++dc) {
            bf16x8_t vf = *(const bf16x8_t*)&Vt[(dc * 16 + r16) * PW + kc2 * 32 + g * 8];
            oacc[dc] = MFMA16(pf, vf, oacc[dc]);
          }
        }
      }
    }
  }

  // merge the 4 lane-groups per row (myrow shared by lanes r16, +16, +32, +48)
#pragma unroll
  for (int off = 16; off <= 32; off <<= 1) l_w += __shfl_xor(l_w, off);
  const float rl2 = 1.0f / l_w;        // frame = m_w (wave-uniform): P = e / l_w

  // O = oacc / l_w(row); rows g*4+j pull that row's l_w via shfl
  float lo[4];
#pragma unroll
  for (int j = 0; j < 4; ++j) lo[j] = 1.0f / __shfl(l_w, g * 4 + j);
#pragma unroll
  for (int dc = 0; dc < 4; ++dc) {
#pragma unroll
    for (int j = 0; j < 4; ++j) {
      int t = wrow0 + g * 4 + j, d = dc * 16 + r16;
      size_t ntok = (size_t)t * BSZ + (bh >> 3);
      attnO[ntok * EMB + (bh & 7) * HD + d] = f2b(oacc[dc][j] * lo[j]);
    }
  }

  // ---------------- pass 2: K-dbuf P streamer (counted-vmcnt sync, T4) ------
  short* Kb0 = lds;          // overlay: Kt
  short* Kb1 = lds + 8192;   // overlay: dead Vt space
  float* Prow = Pout + ((size_t)bh * T_SEQ + myrow) * T_SEQ;

#define STAGEK(KB, BUF)                                                        \
  {                                                                            \
    _Pragma("unroll")                                                          \
    for (int i = 0; i < 4; ++i) {                                              \
      int cc = i * 256 + tid;                                                  \
      int row = cc >> 3, j8 = (cc & 7) ^ (row & 7);                            \
      gload_lds16(Kh + (size_t)((KB) + row) * HD + j8 * 8, &(BUF)[cc * 8]);    \
    }                                                                          \
  }

  __syncthreads();           // pass-1 LDS fully consumed before restaging
  STAGEK(0, Kb0)
  __syncthreads();           // prologue full drain (incl. attnO stores) - once
  int p = 0;
  for (int kt = 0; kt < nt128; ++kt) {
    const int kb = kt * 128;
    short* cur = p ? Kb1 : Kb0;
    short* nxt = p ? Kb0 : Kb1;
    const bool more = (kt + 1 < nt128);
    if (more) {
      STAGEK(kb + 128, nxt)  // overlap staging under compute
      __builtin_amdgcn_sched_barrier(0);   // pin: stores below stay below staging
    }
    const int navail = (maxcol - kb) >> 4;
    const int nkc = navail < 8 ? navail : 8;
#pragma unroll
    for (int kc = 0; kc < 8; ++kc) {
      if (kc < nkc) {
        const int rl = kc * 16 + r16;
        f32x4_t s = {0.f, 0.f, 0.f, 0.f};
#pragma unroll
        for (int kk = 0; kk < 2; ++kk) {
          int byteo = (rl * 128 + kk * 64 + g * 16) ^ ((rl & 7) << 4);
          bf16x8_t kf = *(const bf16x8_t*)((const char*)cur + byteo);
          s = MFMA16(kf, qf[kk], s);   // bit-identical S recompute vs pass 1
        }
        const int key0 = kb + kc * 16 + g * 4;
        float4v pvv;
#pragma unroll
        for (int j = 0; j < 4; ++j) {
          float e = __expf(s[j] * SCALING - m_w) * rl2;
          pvv[j] = (key0 + j <= myrow) ? e : 0.f;
        }
        *(float4v*)(Prow + key0) = pvv;
      }
    }
    if (more) {
      // exactly 8 stores issued after STAGEK -> vmcnt(8) completes the 4
      // staging loads while P stores stay in flight across the barrier (T4)
      __builtin_amdgcn_sched_barrier(0);
      asm volatile("s_waitcnt vmcnt(8)" ::: "memory");
      __builtin_amdgcn_s_barrier();
      __builtin_amdgcn_sched_barrier(0);
    }
    p ^= 1;
  }
}

// ---------------------------------------------------------------------------
extern "C" void kernel_launch(void* const* d_in, const int* in_sizes, int n_in,
                              void* d_out, int out_size, void* d_ws, size_t ws_size,
                              hipStream_t stream) {
  const float* h = (const float*)d_in[0];
  // d_in[1] = attn_mask (causal, applied structurally)
  const float* w_in = (const float*)d_in[2];
  const float* b_in = (const float*)d_in[3];
  const float* w_out = (const float*)d_in[4];
  const float* b_out = (const float*)d_in[5];
  float* out = (float*)d_out;
  float* Pout = out + (size_t)T_SEQ * BSZ * EMB;

  short* hB = (short*)d_ws;                      // 8192*512 bf16
  short* wB = hB + (size_t)8192 * 512;           // 1536*512
  short* owB = wB + (size_t)1536 * 512;          // 512*512
  short* qB = owB + (size_t)512 * 512;           // 32*2048*64 per-head [bh][t][d]
  short* kB = qB + (size_t)32 * 2048 * 64;
  short* vB = kB + (size_t)32 * 2048 * 64;
  short* aB = vB + (size_t)32 * 2048 * 64;       // 8192*512

  cvt3_kernel<<<5120, 256, 0, stream>>>(h, w_in, w_out, hB, wB, owB);

  gemm_bt<0><<<dim3(12, 64), 256, 0, stream>>>(hB, wB, b_in, qB, kB, vB, nullptr);
  attn_fused<<<dim3(32, 32), 256, 0, stream>>>(qB, kB, vB, Pout, aB);
  gemm_bt<1><<<dim3(4, 64), 256, 0, stream>>>(aB, owB, b_out, nullptr, nullptr, nullptr, out);
}